// Round 1
// baseline (41.593 us; speedup 1.0000x reference)
//
#include <hip/hip_runtime.h>

#define HW_  (512*512)
#define NC   16
#define NB   8
#define NPIX (NB*HW_)
#define NGRP (NPIX/4)     // 4 pixels per float4 group
#define GPB  (HW_/4)      // groups per batch image = 65536 (2^16)

// ws[0..15]  = p_sum[c]
// ws[16..31] = intersection[c]
// ws[32..47] = t_sum[c]

__global__ void dice_zero(float* ws) {
    int i = blockIdx.x * blockDim.x + threadIdx.x;
    if (i < 48) ws[i] = 0.0f;
}

__device__ __forceinline__ float wred(float v) {
    v += __shfl_xor(v, 32, 64);
    v += __shfl_xor(v, 16, 64);
    v += __shfl_xor(v,  8, 64);
    v += __shfl_xor(v,  4, 64);
    v += __shfl_xor(v,  2, 64);
    v += __shfl_xor(v,  1, 64);
    return v;
}

__global__ __launch_bounds__(256) void dice_main(
        const float* __restrict__ logits,
        const int*   __restrict__ targets,
        float*       __restrict__ ws) {
    float psum[NC], inter[NC], tsum[NC];
    #pragma unroll
    for (int c = 0; c < NC; ++c) { psum[c] = 0.f; inter[c] = 0.f; tsum[c] = 0.f; }

    const int nthreads = gridDim.x * blockDim.x;
    for (int g = blockIdx.x * blockDim.x + threadIdx.x; g < NGRP; g += nthreads) {
        const int b  = g >> 16;        // g / GPB
        const int s4 = g & (GPB - 1);  // g % GPB
        const float4* lp = reinterpret_cast<const float4*>(logits) + (size_t)b * (NC * GPB) + s4;
        const int4 t = reinterpret_cast<const int4*>(targets)[(size_t)b * GPB + s4];

        float4 e[NC];
        float sx = 0.f, sy = 0.f, sz = 0.f, sw = 0.f;
        #pragma unroll
        for (int c = 0; c < NC; ++c) {
            float4 l = lp[(size_t)c * GPB];
            e[c].x = __expf(l.x); e[c].y = __expf(l.y);
            e[c].z = __expf(l.z); e[c].w = __expf(l.w);
            sx += e[c].x; sy += e[c].y; sz += e[c].z; sw += e[c].w;
        }
        const float ix = __builtin_amdgcn_rcpf(sx);
        const float iy = __builtin_amdgcn_rcpf(sy);
        const float iz = __builtin_amdgcn_rcpf(sz);
        const float iw = __builtin_amdgcn_rcpf(sw);

        #pragma unroll
        for (int c = 0; c < NC; ++c) {
            const float px = e[c].x * ix, py = e[c].y * iy;
            const float pz = e[c].z * iz, pw = e[c].w * iw;
            psum[c] += (px + py) + (pz + pw);
            float ic = 0.f, tc = 0.f;
            if (t.x == c) { ic += px; tc += 1.f; }
            if (t.y == c) { ic += py; tc += 1.f; }
            if (t.z == c) { ic += pz; tc += 1.f; }
            if (t.w == c) { ic += pw; tc += 1.f; }
            inter[c] += ic;
            tsum[c]  += tc;
        }
    }

    // block reduction: wave shuffle-reduce -> LDS -> 48 global atomics
    __shared__ float red[4][48];
    const int lane = threadIdx.x & 63;
    const int wv   = threadIdx.x >> 6;
    #pragma unroll
    for (int c = 0; c < NC; ++c) {
        float a  = wred(psum[c]);
        float bb = wred(inter[c]);
        float cc = wred(tsum[c]);
        if (lane == 0) {
            red[wv][c]        = a;
            red[wv][NC + c]   = bb;
            red[wv][2*NC + c] = cc;
        }
    }
    __syncthreads();
    const int i = threadIdx.x;
    if (i < 48) {
        atomicAdd(&ws[i], red[0][i] + red[1][i] + red[2][i] + red[3][i]);
    }
}

__global__ void dice_final(const float* __restrict__ ws, float* __restrict__ out) {
    if (threadIdx.x == 0 && blockIdx.x == 0) {
        float acc = 0.f;
        #pragma unroll
        for (int c = 0; c < NC; ++c) {
            const float dice = (2.f * ws[NC + c] + 1.f) / (ws[c] + ws[2*NC + c] + 1.f);
            acc += 1.f - dice;
        }
        out[0] = acc * (1.f / 16.f);
    }
}

extern "C" void kernel_launch(void* const* d_in, const int* in_sizes, int n_in,
                              void* d_out, int out_size, void* d_ws, size_t ws_size,
                              hipStream_t stream) {
    const float* logits  = (const float*)d_in[0];
    const int*   targets = (const int*)d_in[1];
    float* ws  = (float*)d_ws;
    float* out = (float*)d_out;

    dice_zero<<<1, 64, 0, stream>>>(ws);
    dice_main<<<512, 256, 0, stream>>>(logits, targets, ws);
    dice_final<<<1, 64, 0, stream>>>(ws, out);
}